// Round 1
// baseline (34.957 us; speedup 1.0000x reference)
//
#include <hip/hip_runtime.h>
#include <hip/hip_bf16.h>

// MyDropout: out = x * mask
//   keep = (u >= 0.1) / 0.9
//   if attack_flag == 1: mask = (col < 64 ? 0 : 1) * keep
//   else:                mask = (col < 64 ? 2.0 : keep)
// x, u: 4096x4096 f32. attack_flag: 1-element int array (read on device).
// Memory-bound: 192 MiB traffic/call.

__global__ __launch_bounds__(256) void MyDropout_11484742550204_kernel(
    const float* __restrict__ x,
    const float* __restrict__ u,
    const int* __restrict__ flag,
    float* __restrict__ out,
    int n_vec,      // number of float4 vectors = N*N/4
    int ncols_vec)  // columns per row in float4 units = 4096/4 = 1024
{
    const int af = *flag;                    // uniform, L2-cached broadcast
    const float INV_KEEP = 1.0f / 0.9f;      // matches f32(1/0.9) in reference
    const int stride = gridDim.x * blockDim.x;

    for (int i = blockIdx.x * blockDim.x + threadIdx.x; i < n_vec; i += stride) {
        const float4 xv = reinterpret_cast<const float4*>(x)[i];
        const float4 uv = reinterpret_cast<const float4*>(u)[i];

        // column (in float4 units) within the row; first 64 cols = first 16 vecs
        const int colv = i & (ncols_vec - 1);
        const bool first_cols = colv < 16;   // 16 float4 = 64 scalar columns

        float4 o;
        if (af == 1) {
            if (first_cols) {
                o = make_float4(0.0f, 0.0f, 0.0f, 0.0f);
            } else {
                o.x = (uv.x >= 0.1f) ? xv.x * INV_KEEP : 0.0f;
                o.y = (uv.y >= 0.1f) ? xv.y * INV_KEEP : 0.0f;
                o.z = (uv.z >= 0.1f) ? xv.z * INV_KEEP : 0.0f;
                o.w = (uv.w >= 0.1f) ? xv.w * INV_KEEP : 0.0f;
            }
        } else {
            if (first_cols) {
                o.x = xv.x * 2.0f;
                o.y = xv.y * 2.0f;
                o.z = xv.z * 2.0f;
                o.w = xv.w * 2.0f;
            } else {
                o.x = (uv.x >= 0.1f) ? xv.x * INV_KEEP : 0.0f;
                o.y = (uv.y >= 0.1f) ? xv.y * INV_KEEP : 0.0f;
                o.z = (uv.z >= 0.1f) ? xv.z * INV_KEEP : 0.0f;
                o.w = (uv.w >= 0.1f) ? xv.w * INV_KEEP : 0.0f;
            }
        }
        reinterpret_cast<float4*>(out)[i] = o;
    }
}

extern "C" void kernel_launch(void* const* d_in, const int* in_sizes, int n_in,
                              void* d_out, int out_size, void* d_ws, size_t ws_size,
                              hipStream_t stream) {
    const float* x   = (const float*)d_in[0];
    const float* u   = (const float*)d_in[1];
    const int* flag  = (const int*)d_in[2];
    float* out       = (float*)d_out;

    const int n = out_size;          // 4096*4096
    const int n_vec = n / 4;         // float4 count
    const int ncols_vec = 4096 / 4;  // 1024

    const int block = 256;
    const int grid = 2048;           // 256 CUs x 8 blocks, grid-stride the rest

    MyDropout_11484742550204_kernel<<<grid, block, 0, stream>>>(
        x, u, flag, out, n_vec, ncols_vec);
}

// Round 2
// 33.427 us; speedup vs baseline: 1.0458x; 1.0458x over previous
//
#include <hip/hip_runtime.h>
#include <hip/hip_bf16.h>

// MyDropout: out = x * mask
//   keep = (u >= 0.1) / 0.9
//   if attack_flag == 1: mask = (col < 64 ? 0 : 1) * keep
//   else:                mask = (col < 64 ? 2.0 : keep)
// x, u: 4096x4096 f32. attack_flag: 1-element int array (read on device).
// Memory-bound. Non-temporal output stores keep x/u resident in L3
// across graph replays (x+u = 128 MiB < 256 MiB Infinity Cache).

__global__ __launch_bounds__(256) void MyDropout_11484742550204_kernel(
    const float* __restrict__ x,
    const float* __restrict__ u,
    const int* __restrict__ flag,
    float* __restrict__ out,
    int n_vec,      // number of float4 vectors = N*N/4
    int ncols_vec)  // columns per row in float4 units = 4096/4 = 1024
{
    const int af = *flag;
    const float INV_KEEP = 1.0f / 0.9f;
    const int stride = gridDim.x * blockDim.x;
    const float4* __restrict__ xv4 = reinterpret_cast<const float4*>(x);
    const float4* __restrict__ uv4 = reinterpret_cast<const float4*>(u);
    float4* __restrict__ ov4 = reinterpret_cast<float4*>(out);

    for (int i = blockIdx.x * blockDim.x + threadIdx.x; i < n_vec; i += stride) {
        const int colv = i & (ncols_vec - 1);
        const bool first_cols = colv < 16;  // 16 float4 = 64 scalar columns

        float4 o;
        if (af == 1) {
            if (first_cols) {
                o = make_float4(0.0f, 0.0f, 0.0f, 0.0f);
            } else {
                const float4 xv = xv4[i];
                const float4 uv = uv4[i];
                o.x = (uv.x >= 0.1f) ? xv.x * INV_KEEP : 0.0f;
                o.y = (uv.y >= 0.1f) ? xv.y * INV_KEEP : 0.0f;
                o.z = (uv.z >= 0.1f) ? xv.z * INV_KEEP : 0.0f;
                o.w = (uv.w >= 0.1f) ? xv.w * INV_KEEP : 0.0f;
            }
        } else {
            const float4 xv = xv4[i];
            if (first_cols) {
                o.x = xv.x * 2.0f;
                o.y = xv.y * 2.0f;
                o.z = xv.z * 2.0f;
                o.w = xv.w * 2.0f;
            } else {
                const float4 uv = uv4[i];
                o.x = (uv.x >= 0.1f) ? xv.x * INV_KEEP : 0.0f;
                o.y = (uv.y >= 0.1f) ? xv.y * INV_KEEP : 0.0f;
                o.z = (uv.z >= 0.1f) ? xv.z * INV_KEEP : 0.0f;
                o.w = (uv.w >= 0.1f) ? xv.w * INV_KEEP : 0.0f;
            }
        }
        // Non-temporal: don't let the output stream evict x/u from L2/L3.
        __builtin_nontemporal_store(o.x, &ov4[i].x);
        __builtin_nontemporal_store(o.y, &ov4[i].y);
        __builtin_nontemporal_store(o.z, &ov4[i].z);
        __builtin_nontemporal_store(o.w, &ov4[i].w);
    }
}

extern "C" void kernel_launch(void* const* d_in, const int* in_sizes, int n_in,
                              void* d_out, int out_size, void* d_ws, size_t ws_size,
                              hipStream_t stream) {
    const float* x   = (const float*)d_in[0];
    const float* u   = (const float*)d_in[1];
    const int* flag  = (const int*)d_in[2];
    float* out       = (float*)d_out;

    const int n = out_size;          // 4096*4096
    const int n_vec = n / 4;         // float4 count
    const int ncols_vec = 4096 / 4;  // 1024

    const int block = 256;
    const int grid = 2048;           // 32 waves/CU, grid-stride

    MyDropout_11484742550204_kernel<<<grid, block, 0, stream>>>(
        x, u, flag, out, n_vec, ncols_vec);
}